// Round 4
// baseline (200.936 us; speedup 1.0000x reference)
//
#include <hip/hip_runtime.h>
#include <hip/hip_bf16.h>
#include <math.h>

#define DM    1024
#define SEQL  2048
#define NB    2
#define MTOT  4096   // NB*SEQL

typedef __attribute__((ext_vector_type(8))) short short8;
typedef __attribute__((ext_vector_type(4))) short short4v;
typedef __attribute__((ext_vector_type(4))) float float4v;

// async global->LDS, 16B per lane; LDS dest is wave-uniform base (+ lane*16 implicit)
#define GLDS16(g, l) __builtin_amdgcn_global_load_lds( \
    (const __attribute__((address_space(1))) void*)(g), \
    (__attribute__((address_space(3))) void*)(l), 16, 0, 0)

__device__ __forceinline__ short f2bf(float f) {
  union { float f; unsigned u; } c; c.f = f;
  unsigned r = c.u + 0x7FFFu + ((c.u >> 16) & 1u);  // RNE
  return (short)(r >> 16);
}

// pack two fp32 -> dword of two bf16 (lo=a, hi=b); round-half-up (cheap, P>=0)
__device__ __forceinline__ int packbf(float a, float b) {
  union { float f; unsigned u; } ca, cb; ca.f = a; cb.f = b;
  return (int)__builtin_amdgcn_perm(cb.u + 0x8000u, ca.u + 0x8000u, 0x07060302u);
}

// One launch converting x + 4 weights fp32->bf16.
__global__ __launch_bounds__(256) void cvt_all(
    const float* __restrict__ x, const float* __restrict__ wq, const float* __restrict__ wk,
    const float* __restrict__ wv, const float* __restrict__ wo,
    short* __restrict__ xb, short* __restrict__ wqb, short* __restrict__ wkb,
    short* __restrict__ wvb, short* __restrict__ wob) {
  const int n4x = MTOT * DM / 4;        // 1,048,576
  int i = blockIdx.x * 256 + threadIdx.x;
  const float* s; short* d; int off;
  if (i < n4x) { s = x; d = xb; off = i; }
  else {
    int j = i - n4x;
    int sel = j >> 18;                  // DM*DM/4 = 262144 = 2^18
    off = j & 0x3FFFF;
    s = (sel == 0) ? wq : (sel == 1) ? wk : (sel == 2) ? wv : wo;
    d = (sel == 0) ? wqb : (sel == 1) ? wkb : (sel == 2) ? wvb : wob;
  }
  float4 v = ((const float4*)s)[off];
  short4v o;
  o.x = f2bf(v.x); o.y = f2bf(v.y); o.z = f2bf(v.z); o.w = f2bf(v.w);
  ((short4v*)d)[off] = o;
}

// Fused QKV projection: blockIdx.z picks Wq/Wk/Wv; z<2 -> RoPE bf16 store
// (z==0 folds 0.125*log2e attention scale into Q), z==2 -> transposed Vt store.
__global__ __launch_bounds__(256, 3) void qkv_kernel(
    const short* __restrict__ A,
    const short* __restrict__ B0, const short* __restrict__ B1, const short* __restrict__ B2,
    short* __restrict__ out0, short* __restrict__ out1, short* __restrict__ out2,
    const float* __restrict__ cosp, const float* __restrict__ sinp)
{
  __shared__ short As[128 * 32];
  __shared__ short Bs[128 * 32];
  const int t = threadIdx.x;
  const int w = t >> 6, lane = t & 63;
  const int quad = lane >> 4, l16 = lane & 15;
  const int wm = w >> 1, wn = w & 1;
  const int bm = blockIdx.y * 128, bn = blockIdx.x * 128;

  const short* Bw = (blockIdx.z == 0) ? B0 : ((blockIdx.z == 1) ? B1 : B2);

  float4v acc[4][4];
#pragma unroll
  for (int i = 0; i < 4; ++i)
#pragma unroll
    for (int j = 0; j < 4; ++j) { float4v z = {0.f, 0.f, 0.f, 0.f}; acc[i][j] = z; }

  for (int k0 = 0; k0 < DM; k0 += 32) {
#pragma unroll
    for (int i = 0; i < 2; ++i) {
      const int c = i * 256 + t;
      const int row = c >> 2, kc = c & 3;
      GLDS16(A  + (size_t)(bm + row) * DM + k0 + kc * 8, As + (i * 256 + w * 64) * 8);
      GLDS16(Bw + (size_t)(bn + row) * DM + k0 + kc * 8, Bs + (i * 256 + w * 64) * 8);
    }
    __syncthreads();
    short8 af[4], bf[4];
#pragma unroll
    for (int mt = 0; mt < 4; ++mt) af[mt] = *(const short8*)&As[(wm * 64 + mt * 16 + l16) * 32 + quad * 8];
#pragma unroll
    for (int nt = 0; nt < 4; ++nt) bf[nt] = *(const short8*)&Bs[(wn * 64 + nt * 16 + l16) * 32 + quad * 8];
#pragma unroll
    for (int mt = 0; mt < 4; ++mt)
#pragma unroll
      for (int nt = 0; nt < 4; ++nt)
        acc[mt][nt] = __builtin_amdgcn_mfma_f32_16x16x32_bf16(af[mt], bf[nt], acc[mt][nt], 0, 0, 0);
    __syncthreads();
  }

  if (blockIdx.z < 2) {
    // RoPE + bf16 store. Wave col-span is 64 = one head; pair (d, d+32) = (nt, nt+2).
    short* qo = (blockIdx.z == 0) ? out0 : out1;
    const float sc = (blockIdx.z == 0) ? 0.18033688011112042f : 1.0f;  // 0.125*log2(e) for Q
#pragma unroll
    for (int mt = 0; mt < 4; ++mt)
#pragma unroll
      for (int r = 0; r < 4; ++r) {
        int grow = bm + wm * 64 + mt * 16 + quad * 4 + r;
        int s = grow & (SEQL - 1);
        int base = grow * DM + bn + wn * 64;
#pragma unroll
        for (int nt = 0; nt < 2; ++nt) {
          int d1 = nt * 16 + l16;  // 0..31
          float q1 = acc[mt][nt][r], q2 = acc[mt][nt + 2][r];
          float c1 = cosp[s * 64 + d1] * sc,      s1 = sinp[s * 64 + d1] * sc;
          float c2 = cosp[s * 64 + 32 + d1] * sc, s2 = sinp[s * 64 + 32 + d1] * sc;
          qo[base + d1]      = f2bf(q1 * c1 - q2 * s1);
          qo[base + 32 + d1] = f2bf(q2 * c2 + q1 * s2);
        }
      }
  } else {
    // V stored transposed: Vt[n][b*S+s], 4 consecutive columns per lane -> 8B stores
    short* vo = out2;
#pragma unroll
    for (int mt = 0; mt < 4; ++mt)
#pragma unroll
      for (int nt = 0; nt < 4; ++nt) {
        int gc = bn + wn * 64 + nt * 16 + l16;
        int g0 = bm + wm * 64 + mt * 16 + quad * 4;
        short4v pk;
#pragma unroll
        for (int r = 0; r < 4; ++r) pk[r] = f2bf(acc[mt][nt][r]);
        *(short4v*)&vo[(size_t)gc * MTOT + g0] = pk;
      }
  }
}

#if __has_builtin(__builtin_amdgcn_mfma_f32_16x16x16bf16_1k)
#define HAVE_MFMA16 1
#define MFMA16(a, b, c) __builtin_amdgcn_mfma_f32_16x16x16bf16_1k(a, b, c, 0, 0, 0)
#else
#define HAVE_MFMA16 0
#endif

// Flash attention v4: balanced q-tile pair (i, 31-i) per block; K/V LDS-staged,
// shared between the two tiles. Computes S^T = mfma(K,Q) so P^T's C-layout is
// directly the B-fragment of 16x16x16 MFMA -> PV straight from registers, no
// P LDS round-trip, no per-iter cross-lane reductions (fixed m=0; scale+log2e
// folded into Q). O accumulated transposed; packed 8B stores at end.
__global__ __launch_bounds__(256, 2) void attn_kernel(
    const short* __restrict__ Q, const short* __restrict__ K,
    const short* __restrict__ Vt, short* __restrict__ O)
{
  __shared__ short Ks[128 * 64];       // 16 KB, chunk-swizzled
  __shared__ short Vs[64 * 128];       // 16 KB, chunk-swizzled
  const int t = threadIdx.x;
  const int w = t >> 6, lane = t & 63;
  const int quad = lane >> 4, l16 = lane & 15;
  const int qtA = blockIdx.x;          // 0..15
  const int qtB = 31 - blockIdx.x;     // 31..16
  const int bh = blockIdx.y;
  const int b = bh >> 4, h = bh & 15;
  const int rowbase = b * SEQL;
  const int colbase = h * 64;
  const int nktA = (qtA >> 1) + 1;     // 1..8   (128-row k-tiles)
  const int nktB = (qtB >> 1) + 1;     // 16..9
  const int qA = qtA * 64 + w * 16 + l16;   // this lane's q (seq-local)
  const int qB = qtB * 64 + w * 16 + l16;

  // Q fragments (lane=q, elems=d) — serve as MFMA B-operand for S^T = K·Q^T
  short8 aqA[2], aqB[2];
#pragma unroll
  for (int kk = 0; kk < 2; ++kk) {
    aqA[kk] = *(const short8*)&Q[(size_t)(rowbase + qA) * DM + colbase + kk * 32 + quad * 8];
    aqB[kk] = *(const short8*)&Q[(size_t)(rowbase + qB) * DM + colbase + kk * 32 + quad * 8];
  }

  float4v odA[4], odB[4];              // O^T: row d=quad*4+r (+dt*16), col q=l16
#pragma unroll
  for (int j = 0; j < 4; ++j) { float4v z = {0.f, 0.f, 0.f, 0.f}; odA[j] = z; odB[j] = z; }
  float lA = 0.f, lB = 0.f;            // per-lane partial row-sums (column q=l16)

  for (int kt = 0; kt < nktB; ++kt) {
    const bool actA = (kt < nktA);
    const bool diagA = (kt == nktA - 1), diagB = (kt == nktB - 1);
    // --- stage K-tile (128 x 64) and V-tile (64 x 128), xor-swizzled chunks ---
    {
      const short* Kbase = K + (size_t)(rowbase + kt * 128) * DM + colbase;
      const short* Vbase = Vt + (size_t)colbase * MTOT + rowbase + kt * 128;
#pragma unroll
      for (int j = 0; j < 4; ++j) {
        int i = j * 256 + t;                       // this lane's chunk id
        int n = i >> 3, c = (i & 7) ^ (n & 7);     // K: row n, global chunk c
        GLDS16(Kbase + (size_t)n * DM + c * 8, Ks + (j * 256 + w * 64) * 8);
      }
#pragma unroll
      for (int j = 0; j < 4; ++j) {
        int i = j * 256 + t;
        int d = i >> 4, c = (i & 15) ^ (d & 7);    // V: row d, global chunk c
        GLDS16(Vbase + (size_t)d * MTOT + c * 8, Vs + (j * 256 + w * 64) * 8);
      }
    }
    __syncthreads();

    // --- S^T = K Q^T per 16-row k-subtile; exp2; pack P^T to bf16 dwords ---
    int pkA[8][2], pkB[8][2];          // [subtile][dw]: dw0 = k quad*4+{0,1}, dw1 = +{2,3}
#pragma unroll
    for (int nt = 0; nt < 8; ++nt) {
      int n = nt * 16 + l16;
      short8 bk0 = *(const short8*)&Ks[(n * 8 + (quad ^ (n & 7))) * 8];
      short8 bk1 = *(const short8*)&Ks[(n * 8 + ((4 + quad) ^ (n & 7))) * 8];
      const int kb = kt * 128 + nt * 16 + quad * 4;     // this lane's k rows
      float4v zz = {0.f, 0.f, 0.f, 0.f};
      float4v sB = __builtin_amdgcn_mfma_f32_16x16x32_bf16(bk0, aqB[0], zz, 0, 0, 0);
      sB = __builtin_amdgcn_mfma_f32_16x16x32_bf16(bk1, aqB[1], sB, 0, 0, 0);
      float pb[4];
#pragma unroll
      for (int r = 0; r < 4; ++r) {
        float p = (diagB && (kb + r > qB)) ? 0.f : __builtin_amdgcn_exp2f(sB[r]);
        lB += p; pb[r] = p;
      }
      pkB[nt][0] = packbf(pb[0], pb[1]);
      pkB[nt][1] = packbf(pb[2], pb[3]);
      if (actA) {
        float4v sA = __builtin_amdgcn_mfma_f32_16x16x32_bf16(bk0, aqA[0], zz, 0, 0, 0);
        sA = __builtin_amdgcn_mfma_f32_16x16x32_bf16(bk1, aqA[1], sA, 0, 0, 0);
        float pa[4];
#pragma unroll
        for (int r = 0; r < 4; ++r) {
          float p = (diagA && (kb + r > qA)) ? 0.f : __builtin_amdgcn_exp2f(sA[r]);
          lA += p; pa[r] = p;
        }
        pkA[nt][0] = packbf(pa[0], pa[1]);
        pkA[nt][1] = packbf(pa[2], pa[3]);
      }
    }

    // --- O^T += V^T P^T ; V^T A-frags from LDS, P^T B-frags = pk (own lane!) ---
#if HAVE_MFMA16
#pragma unroll
    for (int kk = 0; kk < 8; ++kk) {   // 16-wide k chunks
      union { int i[2]; short4v s; } ubB, ubA;
      ubB.i[0] = pkB[kk][0]; ubB.i[1] = pkB[kk][1];
      if (actA) { ubA.i[0] = pkA[kk][0]; ubA.i[1] = pkA[kk][1]; }
#pragma unroll
      for (int dt = 0; dt < 4; ++dt) {
        int d = dt * 16 + l16;
        short4v av = *(const short4v*)&Vs[(d * 16 + ((kk * 2 + (quad >> 1)) ^ (d & 7))) * 8 + (quad & 1) * 4];
        odB[dt] = MFMA16(av, ubB.s, odB[dt]);
        if (actA) odA[dt] = MFMA16(av, ubA.s, odA[dt]);
      }
    }
#else
    // fallback: 16x16x32 PV with cross-quad shuffle assembly of B-frags
#pragma unroll
    for (int kk = 0; kk < 4; ++kk) {
      union { int i[4]; short8 s; } ubB, ubA;
#pragma unroll
      for (int dj = 0; dj < 4; ++dj) {
        int src = (((quad & 1) * 2 + (dj >> 1)) << 4) + l16;
        int b0 = __shfl(pkB[2 * kk][dj & 1], src);
        int b1 = __shfl(pkB[2 * kk + 1][dj & 1], src);
        ubB.i[dj] = (quad >= 2) ? b1 : b0;
        int a0 = __shfl(pkA[2 * kk][dj & 1], src);
        int a1 = __shfl(pkA[2 * kk + 1][dj & 1], src);
        ubA.i[dj] = (quad >= 2) ? a1 : a0;
      }
#pragma unroll
      for (int dt = 0; dt < 4; ++dt) {
        int d = dt * 16 + l16;
        short8 av = *(const short8*)&Vs[(d * 16 + ((kk * 4 + quad) ^ (d & 7))) * 8];
        odB[dt] = __builtin_amdgcn_mfma_f32_16x16x32_bf16(av, ubB.s, odB[dt], 0, 0, 0);
        if (actA) odA[dt] = __builtin_amdgcn_mfma_f32_16x16x32_bf16(av, ubA.s, odA[dt], 0, 0, 0);
      }
    }
#endif
    __syncthreads();
  }

  // --- reduce row-sums across the 4 quads sharing column q=l16 ---
  lA += __shfl_xor(lA, 16); lA += __shfl_xor(lA, 32);
  lB += __shfl_xor(lB, 16); lB += __shfl_xor(lB, 32);
  const float iA = 1.f / lA, iB = 1.f / lB;

  // --- store O (un-transposed on the fly): lane's q fixed, 4 consecutive d per dt ---
#pragma unroll
  for (int dt = 0; dt < 4; ++dt) {
    short4v sa, sb;
#pragma unroll
    for (int r = 0; r < 4; ++r) { sa[r] = f2bf(odA[dt][r] * iA); sb[r] = f2bf(odB[dt][r] * iB); }
    int col = colbase + dt * 16 + quad * 4;
    *(short4v*)&O[(size_t)(rowbase + qA) * DM + col] = sa;
    *(short4v*)&O[(size_t)(rowbase + qB) * DM + col] = sb;
  }
}

// Output projection: out = attn x Wo^T, 128m x 64n tiles (512 blocks), fp32 store.
__global__ __launch_bounds__(256, 2) void gemm_out(
    const short* __restrict__ A, const short* __restrict__ B,
    float* __restrict__ out)
{
  __shared__ short As[128 * 32];
  __shared__ short Bs[64 * 32];
  const int t = threadIdx.x;
  const int w = t >> 6, lane = t & 63;
  const int quad = lane >> 4, l16 = lane & 15;
  const int wm = w >> 1, wn = w & 1;
  const int bm = blockIdx.y * 128, bn = blockIdx.x * 64;

  float4v acc[4][2];
#pragma unroll
  for (int i = 0; i < 4; ++i)
#pragma unroll
    for (int j = 0; j < 2; ++j) { float4v z = {0.f, 0.f, 0.f, 0.f}; acc[i][j] = z; }

  for (int k0 = 0; k0 < DM; k0 += 32) {
#pragma unroll
    for (int i = 0; i < 2; ++i) {
      const int c = i * 256 + t;
      const int row = c >> 2, kc = c & 3;
      GLDS16(A + (size_t)(bm + row) * DM + k0 + kc * 8, As + (i * 256 + w * 64) * 8);
    }
    {
      const int row = t >> 2, kc = t & 3;
      GLDS16(B + (size_t)(bn + row) * DM + k0 + kc * 8, Bs + (w * 64) * 8);
    }
    __syncthreads();
    short8 af[4], bf[2];
#pragma unroll
    for (int mt = 0; mt < 4; ++mt) af[mt] = *(const short8*)&As[(wm * 64 + mt * 16 + l16) * 32 + quad * 8];
#pragma unroll
    for (int nt = 0; nt < 2; ++nt) bf[nt] = *(const short8*)&Bs[(wn * 32 + nt * 16 + l16) * 32 + quad * 8];
#pragma unroll
    for (int mt = 0; mt < 4; ++mt)
#pragma unroll
      for (int nt = 0; nt < 2; ++nt)
        acc[mt][nt] = __builtin_amdgcn_mfma_f32_16x16x32_bf16(af[mt], bf[nt], acc[mt][nt], 0, 0, 0);
    __syncthreads();
  }

#pragma unroll
  for (int mt = 0; mt < 4; ++mt)
#pragma unroll
    for (int nt = 0; nt < 2; ++nt)
#pragma unroll
      for (int r = 0; r < 4; ++r) {
        int grow = bm + wm * 64 + mt * 16 + quad * 4 + r;
        int gcol = bn + wn * 32 + nt * 16 + l16;
        out[(size_t)grow * DM + gcol] = acc[mt][nt][r];
      }
}

extern "C" void kernel_launch(void* const* d_in, const int* in_sizes, int n_in,
                              void* d_out, int out_size, void* d_ws, size_t ws_size,
                              hipStream_t stream) {
  const float* x    = (const float*)d_in[0];
  const float* cosp = (const float*)d_in[1];
  const float* sinp = (const float*)d_in[2];
  const float* Wq   = (const float*)d_in[3];
  const float* Wk   = (const float*)d_in[4];
  const float* Wv   = (const float*)d_in[5];
  const float* Wo   = (const float*)d_in[6];

  char* ws = (char*)d_ws;
  const size_t XB = (size_t)MTOT * DM * 2;  // 8 MB
  const size_t WB = (size_t)DM * DM * 2;    // 2 MB
  short* xb    = (short*)(ws);
  short* wqb   = (short*)(ws + XB);
  short* wkb   = (short*)(ws + XB + 1 * WB);
  short* wvb   = (short*)(ws + XB + 2 * WB);
  short* wob   = (short*)(ws + XB + 3 * WB);
  short* Qb    = (short*)(ws + XB + 4 * WB);
  short* Kb    = (short*)(ws + XB + 4 * WB + XB);
  short* Vtb   = (short*)(ws + XB + 4 * WB + 2 * XB);
  short* attnb = xb;  // x dead after QKV GEMMs; reuse its slot (total ws use: 40 MB)

  const int n4tot = (MTOT * DM + 4 * DM * DM) / 4;  // 2,097,152
  hipLaunchKernelGGL(cvt_all, dim3(n4tot / 256), dim3(256), 0, stream,
                     x, Wq, Wk, Wv, Wo, xb, wqb, wkb, wvb, wob);

  hipLaunchKernelGGL(qkv_kernel, dim3(DM / 128, MTOT / 128, 3), dim3(256), 0, stream,
                     xb, wqb, wkb, wvb, Qb, Kb, Vtb, cosp, sinp);

  hipLaunchKernelGGL(attn_kernel, dim3(16, NB * 16), dim3(256), 0, stream,
                     Qb, Kb, Vtb, attnb);

  hipLaunchKernelGGL(gemm_out, dim3(DM / 64, MTOT / 128), dim3(256), 0, stream,
                     attnb, wob, (float*)d_out);
}